// Round 3
// baseline (10324.054 us; speedup 1.0000x reference)
//
#include <hip/hip_runtime.h>

#define HDIM 32

typedef float v2f __attribute__((ext_vector_type(2)));
typedef unsigned int v2u __attribute__((ext_vector_type(2)));

__device__ inline float fast_exp2(float x) {
#if __has_builtin(__builtin_amdgcn_exp2f)
  return __builtin_amdgcn_exp2f(x);
#else
  return exp2f(x);
#endif
}
__device__ inline float fast_rcp(float x) {
#if __has_builtin(__builtin_amdgcn_rcpf)
  return __builtin_amdgcn_rcpf(x);
#else
  return 1.0f / x;
#endif
}

// lane ^ 32 exchange without an LDS round trip.
__device__ inline float xchg32_for_high(float a) {
#if __has_builtin(__builtin_amdgcn_permlane32_swap)
  v2u r = __builtin_amdgcn_permlane32_swap(
      __float_as_uint(a), __float_as_uint(a), false, false);
  return __uint_as_float(r.x);
#else
  return __shfl_xor(a, 32);
#endif
}
__device__ inline float sum_halves(float p) {
#if __has_builtin(__builtin_amdgcn_permlane32_swap)
  v2u r = __builtin_amdgcn_permlane32_swap(
      __float_as_uint(p), __float_as_uint(p), false, false);
  return __uint_as_float(r.x) + __uint_as_float(r.y);
#else
  return p + __shfl_xor(p, 32);
#endif
}

__device__ inline float bcast_hi(float v, int m) {
  return __int_as_float(__builtin_amdgcn_readlane(__float_as_int(v), 32 + m));
}

// One wave (64 lanes) per batch element.
// Low lane k     owns gate rows j1=k    (i-gate) and j2=64+k (g-gate).
// High lane 32+k owns gate rows j1=32+k (f-gate) and j2=96+k (o-gate).
// State (c,h) for unit k lives in HIGH lane 32+k.
// Per step: one permlane32_swap moves a = sig(i)*tanh(g) low->high.
//
// __launch_bounds__(64, 1): 1 wave/SIMD minimum -> full VGPR budget (512).
// Without this the allocator capped us at 48 VGPRs and rematerialized W_hh
// from global memory inside the step loop (R2 post-mortem).
__global__ __launch_bounds__(64, 1) void lstm_fused(
    const float* __restrict__ x,
    const float* __restrict__ h0,
    const float* __restrict__ c0,
    const float* __restrict__ W_ih,
    const float* __restrict__ W_hh,
    const float* __restrict__ b_ih,
    const float* __restrict__ b_hh,
    const float* __restrict__ W_head,
    const float* __restrict__ b_head,
    float* __restrict__ y,
    int T)
{
  const int lane = threadIdx.x;     // 0..63
  const int b    = blockIdx.x;      // batch
  const int k    = lane & 31;       // hidden unit / output row index
  const int j1   = lane;            // i (low) / f (high) row
  const int j2   = lane + 64;       // g (low) / o (high) row

  // Vector-load the two W_hh rows this lane owns, then pack as float2.
  float rowA[HDIM], rowB[HDIM];
#pragma unroll
  for (int q = 0; q < HDIM / 4; ++q) {
    const float4 va = *reinterpret_cast<const float4*>(W_hh + j1 * HDIM + q * 4);
    const float4 vb = *reinterpret_cast<const float4*>(W_hh + j2 * HDIM + q * 4);
    rowA[q * 4 + 0] = va.x; rowA[q * 4 + 1] = va.y;
    rowA[q * 4 + 2] = va.z; rowA[q * 4 + 3] = va.w;
    rowB[q * 4 + 0] = vb.x; rowB[q * 4 + 1] = vb.y;
    rowB[q * 4 + 2] = vb.z; rowB[q * 4 + 3] = vb.w;
  }
  v2f W12[HDIM];
#pragma unroll
  for (int m = 0; m < HDIM; ++m) { W12[m][0] = rowA[m]; W12[m][1] = rowB[m]; }

  v2f wih;  wih[0]  = W_ih[j1];            wih[1]  = W_ih[j2];
  v2f bias; bias[0] = b_ih[j1] + b_hh[j1]; bias[1] = b_ih[j2] + b_hh[j2];
  const float wh = W_head[k];
  const float bh = b_head[0];

  const bool  low  = lane < HDIM;
  const float LOG2E = 1.4426950408889634f;
  // p2 nonlinearity: low lanes tanh(g2) = 2*sigmoid(2*g2)-1, high lanes sigmoid(g2).
  const float m2L = low ? (-2.0f * LOG2E) : (-LOG2E);
  const float sA  = low ? 2.0f : 1.0f;
  const float bA  = low ? -1.0f : 0.0f;

  float h = h0[k];   // replicated; only high lanes' value matters
  float c = c0[k];

  const float* xb = x + (size_t)b * T;
  float*       yb = y + (size_t)b * T;

  // Head staging: hb[t mod 32][lane] = h*W_head[k]; cols 32..63 valid.
  // Row stride 68 floats -> 16B-aligned rows for b128 reads.
  __shared__ float hb[32][68];

#pragma unroll 1
  for (int t0 = 0; t0 < T; t0 += 32) {
    // 32 uniform x values for this block of steps.
    float xs[32];
#pragma unroll
    for (int q = 0; q < 8; ++q) {
      const float4 v = *reinterpret_cast<const float4*>(xb + t0 + q * 4);
      xs[q * 4 + 0] = v.x; xs[q * 4 + 1] = v.y;
      xs[q * 4 + 2] = v.z; xs[q * 4 + 3] = v.w;
    }

#pragma unroll
    for (int tt = 0; tt < 32; ++tt) {
      const float xt = xs[tt];
      // 4 independent accumulator chains (8 FMAs deep each) -> ILP.
      v2f a0; a0[0] = fmaf(xt, wih[0], bias[0]); a0[1] = fmaf(xt, wih[1], bias[1]);
      v2f a1; a1[0] = 0.f; a1[1] = 0.f;
      v2f a2; a2[0] = 0.f; a2[1] = 0.f;
      v2f a3; a3[0] = 0.f; a3[1] = 0.f;
#pragma unroll
      for (int m = 0; m < HDIM; m += 4) {
        const float h0b = bcast_hi(h, m + 0);
        const float h1b = bcast_hi(h, m + 1);
        const float h2b = bcast_hi(h, m + 2);
        const float h3b = bcast_hi(h, m + 3);
        v2f t;
        t[0] = h0b; t[1] = h0b; a0 = __builtin_elementwise_fma(t, W12[m + 0], a0);
        t[0] = h1b; t[1] = h1b; a1 = __builtin_elementwise_fma(t, W12[m + 1], a1);
        t[0] = h2b; t[1] = h2b; a2 = __builtin_elementwise_fma(t, W12[m + 2], a2);
        t[0] = h3b; t[1] = h3b; a3 = __builtin_elementwise_fma(t, W12[m + 3], a3);
      }
      const v2f g = (a0 + a1) + (a2 + a3);

      // p1 = sigmoid(g1)  (i on low, f on high)
      const float e1 = fast_exp2(g[0] * (-LOG2E));
      const float p1 = fast_rcp(1.0f + e1);
      // p2 = tanh(g2) on low, sigmoid(g2) on high
      const float e2 = fast_exp2(g[1] * m2L);
      const float s2 = fast_rcp(1.0f + e2);
      const float p2 = fmaf(s2, sA, bA);

      const float a  = p1 * p2;              // low: sig(i)*tanh(g)
      const float e  = xchg32_for_high(a);   // high lanes receive low's a

      c = fmaf(p1, c, e);                    // high: sig(f)*c + a (low: bounded junk)
      const float ec = fast_exp2(c * (-2.0f * LOG2E));
      const float tc = fmaf(fast_rcp(1.0f + ec), 2.0f, -1.0f);  // tanh(c)
      h = p2 * tc;                           // high: sig(o)*tanh(c)

      hb[tt][lane] = h * wh;                 // cols 32..63 valid
    }

    // Head: y[t0+r] = sum_{m=0..31} hb[r][32+m] + bh.
    // Low lane r sums cols 32..47 of row r; high lane 32+r sums cols 48..63;
    // permlane32_swap combines the halves.
    {
      const int r = k;
      const float* row = &hb[r][32 + ((lane >> 5) << 4)];
      const float4 s0 = *reinterpret_cast<const float4*>(row + 0);
      const float4 s1 = *reinterpret_cast<const float4*>(row + 4);
      const float4 s2 = *reinterpret_cast<const float4*>(row + 8);
      const float4 s3 = *reinterpret_cast<const float4*>(row + 12);
      const float p = ((s0.x + s0.y) + (s0.z + s0.w))
                    + ((s1.x + s1.y) + (s1.z + s1.w))
                    + ((s2.x + s2.y) + (s2.z + s2.w))
                    + ((s3.x + s3.y) + (s3.z + s3.w));
      const float tot = sum_halves(p) + bh;
      if (lane < 32) yb[t0 + r] = tot;
    }
  }
}

extern "C" void kernel_launch(void* const* d_in, const int* in_sizes, int n_in,
                              void* d_out, int out_size, void* d_ws, size_t ws_size,
                              hipStream_t stream) {
  const float* x      = (const float*)d_in[0];
  const float* h0     = (const float*)d_in[1];
  const float* c0     = (const float*)d_in[2];
  const float* W_ih   = (const float*)d_in[3];
  const float* W_hh   = (const float*)d_in[4];
  const float* b_ih   = (const float*)d_in[5];
  const float* b_hh   = (const float*)d_in[6];
  const float* W_head = (const float*)d_in[7];
  const float* b_head = (const float*)d_in[8];
  float* yout = (float*)d_out;

  const int B = 64;
  const int T = in_sizes[0] / B;   // 48384, divisible by 32

  lstm_fused<<<dim3(B), dim3(64), 0, stream>>>(
      x, h0, c0, W_ih, W_hh, b_ih, b_hh, W_head, b_head, yout, T);
}

// Round 7
// 9784.476 us; speedup vs baseline: 1.0551x; 1.0551x over previous
//
#include <hip/hip_runtime.h>

#define HDIM 32

typedef float v2f __attribute__((ext_vector_type(2)));
typedef unsigned int v2u __attribute__((ext_vector_type(2)));

// Pin a value into a VGPR: the empty asm makes the SSA value an asm output,
// which LLVM's RA cannot rematerialize (unlike invariant loads, which it
// happily re-issues inside the loop instead of keeping them resident --
// that was R2/R3's ~360 stall cycles/step).
#define KEEPF(v) asm("" : "+v"(v))

__device__ inline float fast_exp2(float x) {
#if __has_builtin(__builtin_amdgcn_exp2f)
  return __builtin_amdgcn_exp2f(x);
#else
  return exp2f(x);
#endif
}
__device__ inline float fast_rcp(float x) {
#if __has_builtin(__builtin_amdgcn_rcpf)
  return __builtin_amdgcn_rcpf(x);
#else
  return 1.0f / x;
#endif
}

// lane ^ 32 exchange without an LDS round trip.
__device__ inline float xchg32_for_high(float a) {
#if __has_builtin(__builtin_amdgcn_permlane32_swap)
  v2u r = __builtin_amdgcn_permlane32_swap(
      __float_as_uint(a), __float_as_uint(a), false, false);
  return __uint_as_float(r.x);
#else
  return __shfl_xor(a, 32);
#endif
}
__device__ inline float sum_halves(float p) {
#if __has_builtin(__builtin_amdgcn_permlane32_swap)
  v2u r = __builtin_amdgcn_permlane32_swap(
      __float_as_uint(p), __float_as_uint(p), false, false);
  return __uint_as_float(r.x) + __uint_as_float(r.y);
#else
  return p + __shfl_xor(p, 32);
#endif
}

__device__ inline float bcast_hi(float v, int m) {
  return __int_as_float(__builtin_amdgcn_readlane(__float_as_int(v), 32 + m));
}

// One wave (64 lanes) per batch element.
// Low lane k     owns gate rows j1=k    (i-gate) and j2=64+k (g-gate).
// High lane 32+k owns gate rows j1=32+k (f-gate) and j2=96+k (o-gate).
// State (c,h) for unit k lives in HIGH lane 32+k.
// Per step: one permlane32_swap moves a = sig(i)*tanh(g) low->high.
__global__ __launch_bounds__(64)
__attribute__((amdgpu_waves_per_eu(1, 1)))
void lstm_fused(
    const float* __restrict__ x,
    const float* __restrict__ h0,
    const float* __restrict__ c0,
    const float* __restrict__ W_ih,
    const float* __restrict__ W_hh,
    const float* __restrict__ b_ih,
    const float* __restrict__ b_hh,
    const float* __restrict__ W_head,
    const float* __restrict__ b_head,
    float* __restrict__ y,
    int T)
{
  const int lane = threadIdx.x;     // 0..63
  const int b    = blockIdx.x;      // batch
  const int k    = lane & 31;       // hidden unit / output row index
  const int j1   = lane;            // i (low) / f (high) row
  const int j2   = lane + 64;       // g (low) / o (high) row

  // Load the two W_hh rows this lane owns; pin every element into a VGPR.
  v2f W12[HDIM];
#pragma unroll
  for (int q = 0; q < HDIM / 4; ++q) {
    const float4 va = *reinterpret_cast<const float4*>(W_hh + j1 * HDIM + q * 4);
    const float4 vb = *reinterpret_cast<const float4*>(W_hh + j2 * HDIM + q * 4);
    W12[q * 4 + 0][0] = va.x; W12[q * 4 + 1][0] = va.y;
    W12[q * 4 + 2][0] = va.z; W12[q * 4 + 3][0] = va.w;
    W12[q * 4 + 0][1] = vb.x; W12[q * 4 + 1][1] = vb.y;
    W12[q * 4 + 2][1] = vb.z; W12[q * 4 + 3][1] = vb.w;
  }
#pragma unroll
  for (int m = 0; m < HDIM; ++m) { KEEPF(W12[m][0]); KEEPF(W12[m][1]); }

  v2f wih;  wih[0]  = W_ih[j1];            wih[1]  = W_ih[j2];
  v2f bias; bias[0] = b_ih[j1] + b_hh[j1]; bias[1] = b_ih[j2] + b_hh[j2];
  KEEPF(wih[0]); KEEPF(wih[1]); KEEPF(bias[0]); KEEPF(bias[1]);
  float wh = W_head[k];
  float bh = b_head[0];
  KEEPF(wh); KEEPF(bh);

  const bool  low  = lane < HDIM;
  const float LOG2E = 1.4426950408889634f;
  // p2 nonlinearity: low lanes tanh(g2) = 2*sigmoid(2*g2)-1, high lanes sigmoid(g2).
  float m2L = low ? (-2.0f * LOG2E) : (-LOG2E);
  float sA  = low ? 2.0f : 1.0f;
  float bA  = low ? -1.0f : 0.0f;
  KEEPF(m2L); KEEPF(sA); KEEPF(bA);

  float h = h0[k];   // replicated; only high lanes' value matters
  float c = c0[k];

  const float* xb = x + (size_t)b * T;
  float*       yb = y + (size_t)b * T;

  // Head staging: hb[t mod 32][lane] = h*W_head[k]; cols 32..63 valid.
  // Row stride 68 floats -> 16B-aligned rows for b128 reads.
  __shared__ float hb[32][68];

#pragma unroll 1
  for (int t0 = 0; t0 < T; t0 += 32) {
    // 32 uniform x values for this block of steps; pinned so they are not
    // re-fetched mid-loop.
    float xs[32];
#pragma unroll
    for (int q = 0; q < 8; ++q) {
      float4 v = *reinterpret_cast<const float4*>(xb + t0 + q * 4);
      KEEPF(v.x); KEEPF(v.y); KEEPF(v.z); KEEPF(v.w);
      xs[q * 4 + 0] = v.x; xs[q * 4 + 1] = v.y;
      xs[q * 4 + 2] = v.z; xs[q * 4 + 3] = v.w;
    }

#pragma unroll
    for (int tt = 0; tt < 32; ++tt) {
      const float xt = xs[tt];
      // 4 independent accumulator chains (8 FMAs deep each) -> ILP.
      v2f a0; a0[0] = fmaf(xt, wih[0], bias[0]); a0[1] = fmaf(xt, wih[1], bias[1]);
      v2f a1; a1[0] = 0.f; a1[1] = 0.f;
      v2f a2; a2[0] = 0.f; a2[1] = 0.f;
      v2f a3; a3[0] = 0.f; a3[1] = 0.f;
#pragma unroll
      for (int m = 0; m < HDIM; m += 4) {
        const float h0b = bcast_hi(h, m + 0);
        const float h1b = bcast_hi(h, m + 1);
        const float h2b = bcast_hi(h, m + 2);
        const float h3b = bcast_hi(h, m + 3);
        v2f t;
        t[0] = h0b; t[1] = h0b; a0 = __builtin_elementwise_fma(t, W12[m + 0], a0);
        t[0] = h1b; t[1] = h1b; a1 = __builtin_elementwise_fma(t, W12[m + 1], a1);
        t[0] = h2b; t[1] = h2b; a2 = __builtin_elementwise_fma(t, W12[m + 2], a2);
        t[0] = h3b; t[1] = h3b; a3 = __builtin_elementwise_fma(t, W12[m + 3], a3);
      }
      const v2f g = (a0 + a1) + (a2 + a3);

      // p1 = sigmoid(g1)  (i on low, f on high)
      const float e1 = fast_exp2(g[0] * (-LOG2E));
      const float p1 = fast_rcp(1.0f + e1);
      // p2 = tanh(g2) on low, sigmoid(g2) on high
      const float e2 = fast_exp2(g[1] * m2L);
      const float s2 = fast_rcp(1.0f + e2);
      const float p2 = fmaf(s2, sA, bA);

      const float a  = p1 * p2;              // low: sig(i)*tanh(g)
      const float e  = xchg32_for_high(a);   // high lanes receive low's a

      c = fmaf(p1, c, e);                    // high: sig(f)*c + a (low: bounded junk)
      const float ec = fast_exp2(c * (-2.0f * LOG2E));
      const float tc = fmaf(fast_rcp(1.0f + ec), 2.0f, -1.0f);  // tanh(c)
      h = p2 * tc;                           // high: sig(o)*tanh(c)

      hb[tt][lane] = h * wh;                 // cols 32..63 valid
    }

    // Head: y[t0+r] = sum_{m=0..31} hb[r][32+m] + bh.
    // Low lane r sums cols 32..47 of row r; high lane 32+r sums cols 48..63;
    // permlane32_swap combines the halves.
    {
      const int r = k;
      const float* row = &hb[r][32 + ((lane >> 5) << 4)];
      const float4 s0 = *reinterpret_cast<const float4*>(row + 0);
      const float4 s1 = *reinterpret_cast<const float4*>(row + 4);
      const float4 s2 = *reinterpret_cast<const float4*>(row + 8);
      const float4 s3 = *reinterpret_cast<const float4*>(row + 12);
      const float p = ((s0.x + s0.y) + (s0.z + s0.w))
                    + ((s1.x + s1.y) + (s1.z + s1.w))
                    + ((s2.x + s2.y) + (s2.z + s2.w))
                    + ((s3.x + s3.y) + (s3.z + s3.w));
      const float tot = sum_halves(p) + bh;
      if (lane < 32) yb[t0 + r] = tot;
    }
  }
}

extern "C" void kernel_launch(void* const* d_in, const int* in_sizes, int n_in,
                              void* d_out, int out_size, void* d_ws, size_t ws_size,
                              hipStream_t stream) {
  const float* x      = (const float*)d_in[0];
  const float* h0     = (const float*)d_in[1];
  const float* c0     = (const float*)d_in[2];
  const float* W_ih   = (const float*)d_in[3];
  const float* W_hh   = (const float*)d_in[4];
  const float* b_ih   = (const float*)d_in[5];
  const float* b_hh   = (const float*)d_in[6];
  const float* W_head = (const float*)d_in[7];
  const float* b_head = (const float*)d_in[8];
  float* yout = (float*)d_out;

  const int B = 64;
  const int T = in_sizes[0] / B;   // 48384, divisible by 32

  lstm_fused<<<dim3(B), dim3(64), 0, stream>>>(
      x, h0, c0, W_ih, W_hh, b_ih, b_hh, W_head, b_head, yout, T);
}